// Round 9
// baseline (190.116 us; speedup 1.0000x reference)
//
#include <hip/hip_runtime.h>
#include <hip/hip_bf16.h>
#include <stdint.h>

// B=4, C=16, n=1024, T=16, Ks=3
// out = softmax_c( cosatt(x) * relu(Gconv(x) + x) ), [4,16,1024,16] fp32

using short8v = __attribute__((ext_vector_type(8))) short;
using float4v = __attribute__((ext_vector_type(4))) float;

#define MFMA16(a, b, c) __builtin_amdgcn_mfma_f32_16x16x32_bf16(a, b, c, 0, 0, 0)

// ---- workspace layout (bytes) -- total 46,137,344 ----
static constexpr size_t M1_OFF  = 0;          // 1024x3072 f32
static constexpr size_t O_OFF   = 12582912;   // 64x1024x16 f32 (attention out)
static constexpr size_t XSH_OFF = 16777216;   // x-hat S-frag layout hi  (64bc x 64rf x 64lane x 16B)
static constexpr size_t XSL_OFF = 20971520;   //                     lo
static constexpr size_t XTH_OFF = 25165824;   // RAW-x^T PV-frag layout hi (64bc x 32g32 x 64lane x 16B)
static constexpr size_t XTL_OFF = 27262976;   //                        lo
static constexpr size_t AGH_OFF = 29360128;   // GEMM A hi (8tm x 32tk x 512ch x 16B)
static constexpr size_t AGL_OFF = 31457280;
static constexpr size_t BGH_OFF = 33554432;   // GEMM B hi (24tn x 32tk x 512ch x 16B)
static constexpr size_t BGL_OFF = 39845888;

__device__ __forceinline__ float fast_rcp(float x) {
  float r; asm("v_rcp_f32 %0, %1" : "=v"(r) : "v"(x)); return r;
}
__device__ __forceinline__ unsigned f2u(float f) { union { float f; unsigned u; } v; v.f = f; return v.u; }
__device__ __forceinline__ float u2f(unsigned u) { union { unsigned u; float f; } v; v.u = u; return v.f; }
__device__ __forceinline__ unsigned short f2bf(float f) {
  unsigned u = f2u(f);
  return (unsigned short)((u + 0x7FFFu + ((u >> 16) & 1u)) >> 16);  // RNE
}
__device__ __forceinline__ float bf2f(unsigned short h) { return u2f(((unsigned)h) << 16); }

typedef const __attribute__((address_space(1))) unsigned int* gas1_t;
typedef __attribute__((address_space(3))) unsigned int* las3_t;
__device__ __forceinline__ void gload16(const void* g, void* l) {
  __builtin_amdgcn_global_load_lds((gas1_t)g, (las3_t)l, 16, 0, 0);
}

// ---------------------------------------------------------------------------
// prep_gemm: split X_tmp and Lk into bf16 hi/lo in fragment-tile-linear order.
// ---------------------------------------------------------------------------
__global__ __launch_bounds__(256) void prep_gemm(const float* __restrict__ x,
                                                 const float* __restrict__ Lk,
                                                 void* __restrict__ ws) {
  const int n = blockIdx.x * 256 + threadIdx.x;
  short8v hv, lv;
  if (n < 131072) {  // A chunks: X_tmp[row][k] = x[(row>>4)*16384 + k*16 + (row&15)]
    const int r = n & 15, g = (n >> 4) & 3, f = (n >> 6) & 7, tk = (n >> 9) & 31, tm = n >> 14;
    const float* p = x + (size_t)(tm * 8 + f) * 16384 + (size_t)(tk * 32 + g * 8) * 16 + r;
#pragma unroll
    for (int j = 0; j < 8; ++j) {
      float v = p[j * 16];
      unsigned short h = f2bf(v);
      hv[j] = (short)h; lv[j] = (short)f2bf(v - bf2f(h));
    }
    ((short8v*)((char*)ws + AGH_OFF))[n] = hv;
    ((short8v*)((char*)ws + AGL_OFF))[n] = lv;
  } else {  // B chunks from Lk[k][col]
    const int nb = n - 131072;
    const int r = nb & 15, g = (nb >> 4) & 3, f = (nb >> 6) & 7, tk = (nb >> 9) & 31, tn = nb >> 14;
    const float* p = Lk + (size_t)(tk * 32 + g * 8) * 3072 + tn * 128 + f * 16 + r;
#pragma unroll
    for (int j = 0; j < 8; ++j) {
      float v = p[(size_t)j * 3072];
      unsigned short h = f2bf(v);
      hv[j] = (short)h; lv[j] = (short)f2bf(v - bf2f(h));
    }
    ((short8v*)((char*)ws + BGH_OFF))[nb] = hv;
    ((short8v*)((char*)ws + BGL_OFF))[nb] = lv;
  }
}

// ---------------------------------------------------------------------------
// prep_attn: XS = bf16 hi/lo of x-hat (S-operand frags, lanes>=32 zero pad);
// XT = bf16 hi/lo of RAW x transposed (PV B-frags). (R4 fix: PV uses raw x.)
// ---------------------------------------------------------------------------
__global__ __launch_bounds__(256) void prep_attn(const float* __restrict__ x,
                                                 void* __restrict__ ws) {
  __shared__ float xs[256 * 16];  // RAW x slab
  const int tid = threadIdx.x;
  const int bc = blockIdx.x >> 2, ss = blockIdx.x & 3;
  const float* xb = x + (size_t)bc * 16384 + (size_t)ss * 4096;
#pragma unroll
  for (int r = 0; r < 4; ++r) ((float4*)xs)[r * 256 + tid] = ((const float4*)xb)[r * 256 + tid];
  __syncthreads();
  float v[16];
#pragma unroll
  for (int q = 0; q < 4; ++q) {
    float4 t4 = ((float4*)xs)[tid * 4 + q];
    v[q * 4] = t4.x; v[q * 4 + 1] = t4.y; v[q * 4 + 2] = t4.z; v[q * 4 + 3] = t4.w;
  }
  float s2 = 0.f;
#pragma unroll
  for (int t = 0; t < 16; ++t) s2 += v[t] * v[t];
  const float rn = fast_rcp(sqrtf(s2));
#pragma unroll
  for (int t = 0; t < 16; ++t) v[t] *= rn;
  unsigned short hh[16], ll[16];
#pragma unroll
  for (int t = 0; t < 16; ++t) { hh[t] = f2bf(v[t]); ll[t] = f2bf(v[t] - bf2f(hh[t])); }
  short8v h0, h1, l0, l1, zz;
#pragma unroll
  for (int j = 0; j < 8; ++j) {
    h0[j] = (short)hh[j]; h1[j] = (short)hh[8 + j];
    l0[j] = (short)ll[j]; l1[j] = (short)ll[8 + j]; zz[j] = 0;
  }
  const int rf = ss * 16 + (tid >> 4);
  short8v* XSh = (short8v*)((char*)ws + XSH_OFF);
  short8v* XSl = (short8v*)((char*)ws + XSL_OFF);
  const size_t base = ((size_t)bc * 64 + rf) * 64;
  const int lo = tid & 15;
  XSh[base + lo] = h0;       XSh[base + 16 + lo] = h1;
  XSh[base + 32 + lo] = zz;  XSh[base + 48 + lo] = zz;
  XSl[base + lo] = l0;       XSl[base + 16 + lo] = l1;
  XSl[base + 32 + lo] = zz;  XSl[base + 48 + lo] = zz;
  // XT gather from RAW xs: chunk (jt_l, lane): t = lane&15, j = jt_l*32 + (lane>>4)*8 + jj
  short8v* XTh = (short8v*)((char*)ws + XTH_OFF);
  short8v* XTl = (short8v*)((char*)ws + XTL_OFF);
#pragma unroll
  for (int rep = 0; rep < 2; ++rep) {
    const int idx = rep * 256 + tid;
    const int jt_l = idx >> 6, l = idx & 63;
    const int t = l & 15, jb = jt_l * 32 + ((l >> 4) << 3);
    short8v ph, pl;
#pragma unroll
    for (int jj = 0; jj < 8; ++jj) {
      float xv = xs[(jb + jj) * 16 + t];
      unsigned short h = f2bf(xv);
      ph[jj] = (short)h; pl[jj] = (short)f2bf(xv - bf2f(h));
    }
    const size_t ci = ((size_t)bc * 32 + ss * 8 + jt_l) * 64 + l;
    XTh[ci] = ph; XTl[ci] = pl;
  }
}

// ---------------------------------------------------------------------------
// gemm_mfma: M1 = X_tmp @ Lk via split-bf16 (AhBh + AlBh + AhBl).
// 128x128 tile, 512 thr (8 waves 2x4), BK=32, double-buffered global_load_lds.
// (R5-exact — passing configuration.)
// ---------------------------------------------------------------------------
__global__ __launch_bounds__(512) void gemm_mfma(void* __restrict__ ws) {
  __shared__ unsigned short AhL[2][4096], AlL[2][4096], BhL[2][4096], BlL[2][4096];
  const int tid = threadIdx.x, lane = tid & 63, w = tid >> 6;
  const int wm = w >> 2, wn = w & 3;
  const int bn = blockIdx.x, bm = blockIdx.y;
  const short8v* Agh = (const short8v*)((char*)ws + AGH_OFF);
  const short8v* Agl = (const short8v*)((char*)ws + AGL_OFF);
  const short8v* Bgh = (const short8v*)((char*)ws + BGH_OFF);
  const short8v* Bgl = (const short8v*)((char*)ws + BGL_OFF);
  float* M1 = (float*)((char*)ws + M1_OFF);
  float4v acc[4][2] = {};

  auto stage = [&](int tk, int bb) {
    gload16(&Agh[(size_t)(bm * 32 + tk) * 512 + tid], &AhL[bb][tid * 8]);
    gload16(&Agl[(size_t)(bm * 32 + tk) * 512 + tid], &AlL[bb][tid * 8]);
    gload16(&Bgh[(size_t)(bn * 32 + tk) * 512 + tid], &BhL[bb][tid * 8]);
    gload16(&Bgl[(size_t)(bn * 32 + tk) * 512 + tid], &BlL[bb][tid * 8]);
  };
  stage(0, 0);
  __syncthreads();
  for (int tk = 0; tk < 32; ++tk) {
    const int bb = tk & 1;
    if (tk < 31) stage(tk + 1, bb ^ 1);
    short8v ah[4], al[4], bh[2], bl[2];
#pragma unroll
    for (int fm = 0; fm < 4; ++fm) {
      ah[fm] = *(const short8v*)&AhL[bb][((wm * 4 + fm) * 64 + lane) * 8];
      al[fm] = *(const short8v*)&AlL[bb][((wm * 4 + fm) * 64 + lane) * 8];
    }
#pragma unroll
    for (int fn = 0; fn < 2; ++fn) {
      bh[fn] = *(const short8v*)&BhL[bb][((wn * 2 + fn) * 64 + lane) * 8];
      bl[fn] = *(const short8v*)&BlL[bb][((wn * 2 + fn) * 64 + lane) * 8];
    }
#pragma unroll
    for (int fm = 0; fm < 4; ++fm)
#pragma unroll
      for (int fn = 0; fn < 2; ++fn) {
        acc[fm][fn] = MFMA16(ah[fm], bh[fn], acc[fm][fn]);
        acc[fm][fn] = MFMA16(al[fm], bh[fn], acc[fm][fn]);
        acc[fm][fn] = MFMA16(ah[fm], bl[fn], acc[fm][fn]);
      }
    __syncthreads();
  }
  // C/D: col = lane&15, row = (lane>>4)*4 + reg  (R2-verified)
#pragma unroll
  for (int fm = 0; fm < 4; ++fm)
#pragma unroll
    for (int fn = 0; fn < 2; ++fn) {
      const int col = bn * 128 + (wn * 2 + fn) * 16 + (lane & 15);
      const int rowb = bm * 128 + (wm * 4 + fm) * 16 + ((lane >> 4) << 2);
#pragma unroll
      for (int r = 0; r < 4; ++r) M1[(size_t)(rowb + r) * 3072 + col] = acc[fm][fn][r];
    }
}

// ---------------------------------------------------------------------------
// attn_mfma: R5-exact passing structure (non-swapped S, scalar f2bf packing,
// b16-scatter Pbuf) with exactly TWO bounded changes:
//   (1) x^T PV operands read straight into registers from the same global
//       chunks R5 staged through LDS (identical chunk index math);
//   (2) LDS 57KB -> 40KB => __launch_bounds__(256,4), 4 blocks/CU.
// ---------------------------------------------------------------------------
__global__ __launch_bounds__(256, 4) void attn_mfma(const float* __restrict__ beta,
                                                    void* __restrict__ ws) {
  __shared__ unsigned short XShL[2][4096], XSlL[2][4096];  // 16KB + 16KB
  __shared__ unsigned short Pbuf[4][1024];  // per-wave: Ph [0..511], Pl [512..1023]
  const int tid = threadIdx.x, lane = tid & 63, w = tid >> 6;
  const int bc = blockIdx.x >> 3, slab = blockIdx.x & 7;
  const short8v* XSgh = (const short8v*)((char*)ws + XSH_OFF);
  const short8v* XSgl = (const short8v*)((char*)ws + XSL_OFF);
  const short8v* XTgh = (const short8v*)((char*)ws + XTH_OFF);
  const short8v* XTgl = (const short8v*)((char*)ws + XTL_OFF);
  float* O = (float*)((char*)ws + O_OFF);

  short8v ah[2], al[2];
#pragma unroll
  for (int m = 0; m < 2; ++m) {
    const int ifr = slab * 8 + w * 2 + m;
    ah[m] = XSgh[((size_t)bc * 64 + ifr) * 64 + lane];
    al[m] = XSgl[((size_t)bc * 64 + ifr) * 64 + lane];
  }
  float4v o[2] = {};

  auto stage = [&](int jt, int bb) {
    const short8v* sh = XSgh + (size_t)bc * 4096 + jt * 512;
    const short8v* sl = XSgl + (size_t)bc * 4096 + jt * 512;
    gload16(&sh[tid], &XShL[bb][tid * 8]);
    gload16(&sh[256 + tid], &XShL[bb][(256 + tid) * 8]);
    gload16(&sl[tid], &XSlL[bb][tid * 8]);
    gload16(&sl[256 + tid], &XSlL[bb][(256 + tid) * 8]);
  };
  stage(0, 0);
  __syncthreads();

  unsigned short* pb = &Pbuf[w][0];
  for (int jt = 0; jt < 8; ++jt) {
    const int bb = jt & 1;
    if (jt < 7) stage(jt + 1, bb ^ 1);
    // (1) PV B-operands: same chunks R5 staged, now per-lane register loads
    short8v xth[4], xtl[4];
#pragma unroll
    for (int kk = 0; kk < 4; ++kk) {
      xth[kk] = XTgh[(size_t)bc * 2048 + jt * 256 + kk * 64 + lane];
      xtl[kk] = XTgl[(size_t)bc * 2048 + jt * 256 + kk * 64 + lane];
    }
#pragma unroll
    for (int m = 0; m < 2; ++m) {
      const int ib = slab * 128 + (w * 2 + m) * 16 + ((lane >> 4) << 2);
#pragma unroll
      for (int kk = 0; kk < 4; ++kk) {
#pragma unroll
        for (int fh = 0; fh < 2; ++fh) {
          const int f = kk * 2 + fh;
          short8v bhv = *(const short8v*)&XShL[bb][(f * 64 + lane) * 8];
          short8v blv = *(const short8v*)&XSlL[bb][(f * 64 + lane) * 8];
          float4v s = {0.f, 0.f, 0.f, 0.f};
          s = MFMA16(ah[m], bhv, s);
          s = MFMA16(al[m], bhv, s);
          s = MFMA16(ah[m], blv, s);
          const float* bp = beta + (size_t)ib * 1024 + jt * 128 + f * 16 + (lane & 15);
#pragma unroll
          for (int r = 0; r < 4; ++r) {
            const float z = bp[(size_t)r * 1024] * s[r];   // beta * cos
            const float p = fast_rcp(1.f + __expf(-z));    // sigmoid
            const unsigned short ph = f2bf(p);
            const unsigned short pl = f2bf(p - bf2f(ph));
            const int i = ((lane >> 4) << 2) + r;
            const int jl = fh * 16 + (lane & 15);
            const int sidx = (((jl >> 3) << 4) | i) * 8 + (jl & 7);  // frag-linear
            pb[sidx] = ph;
            pb[512 + sidx] = pl;
          }
        }
        short8v pha = *(const short8v*)&pb[lane * 8];
        short8v pla = *(const short8v*)&pb[512 + lane * 8];
        o[m] = MFMA16(pha, xth[kk], o[m]);
        o[m] = MFMA16(pla, xth[kk], o[m]);
        o[m] = MFMA16(pha, xtl[kk], o[m]);
      }
    }
    __syncthreads();
  }
#pragma unroll
  for (int m = 0; m < 2; ++m)
#pragma unroll
    for (int r = 0; r < 4; ++r) {
      const int ig = slab * 128 + (w * 2 + m) * 16 + ((lane >> 4) << 2) + r;
      O[((size_t)bc * 1024 + ig) * 16 + (lane & 15)] = o[m][r];
    }
}

// ---------------------------------------------------------------------------
// tail_fuse: g = theta-contraction of M1 (LDS-staged slab), logit =
// O * relu(g + x), softmax over c in-register via 16-lane shfl_xor.
// ---------------------------------------------------------------------------
__global__ __launch_bounds__(256) void tail_fuse(const float* __restrict__ x,
                                                 const float* __restrict__ theta,
                                                 const float* __restrict__ bias,
                                                 const void* __restrict__ ws,
                                                 float* __restrict__ out) {
  __shared__ float m1s[48 * 256];  // [tauk][t][i]
  __shared__ float ths[768];
  const int tid = threadIdx.x;
  const int b = blockIdx.x >> 6, chunk = blockIdx.x & 63, i0 = chunk * 16;
  const float* M1 = (const float*)((const char*)ws + M1_OFF);
  const float* O = (const float*)((const char*)ws + O_OFF);
  {
    const int i = tid & 15, t = tid >> 4;
#pragma unroll
    for (int s = 0; s < 48; ++s)
      m1s[(s * 16 + t) * 16 + i] =
          M1[(size_t)((b * 16 + t) * 16 + s / 3) * 3072 + (s % 3) * 1024 + i0 + i];
  }
#pragma unroll
  for (int r = 0; r < 3; ++r) ths[r * 256 + tid] = theta[r * 256 + tid];
  __syncthreads();
  const int c = tid & 15, t = tid >> 4;
  const int bc = b * 16 + c;
  float xv[16], ov[16];
#pragma unroll
  for (int i = 0; i < 16; ++i) {
    const size_t a = ((size_t)bc * 1024 + i0 + i) * 16 + t;
    xv[i] = x[a]; ov[i] = O[a];
  }
  float thc[48];
#pragma unroll
  for (int s = 0; s < 48; ++s) thc[s] = ths[s * 16 + c];
  float g[16];
  const float bs = bias[c];
#pragma unroll
  for (int i = 0; i < 16; ++i) g[i] = bs;
#pragma unroll
  for (int s = 0; s < 48; ++s) {
    const float4* mp = (const float4*)&m1s[(s * 16 + t) * 16];
    const float th = thc[s];
#pragma unroll
    for (int q = 0; q < 4; ++q) {
      float4 mv = mp[q];
      g[q * 4] += mv.x * th; g[q * 4 + 1] += mv.y * th;
      g[q * 4 + 2] += mv.z * th; g[q * 4 + 3] += mv.w * th;
    }
  }
  float lg[16];
#pragma unroll
  for (int i = 0; i < 16; ++i) lg[i] = ov[i] * fmaxf(g[i] + xv[i], 0.f);
#pragma unroll
  for (int i = 0; i < 16; ++i) {
    float mx = lg[i];
    mx = fmaxf(mx, __shfl_xor(mx, 1)); mx = fmaxf(mx, __shfl_xor(mx, 2));
    mx = fmaxf(mx, __shfl_xor(mx, 4)); mx = fmaxf(mx, __shfl_xor(mx, 8));
    const float e = __expf(lg[i] - mx);
    float sm = e;
    sm += __shfl_xor(sm, 1); sm += __shfl_xor(sm, 2);
    sm += __shfl_xor(sm, 4); sm += __shfl_xor(sm, 8);
    out[((size_t)bc * 1024 + i0 + i) * 16 + t] = e * fast_rcp(sm);
  }
}

// ---------------------------------------------------------------------------
extern "C" void kernel_launch(void* const* d_in, const int* in_sizes, int n_in,
                              void* d_out, int out_size, void* d_ws, size_t ws_size,
                              hipStream_t stream) {
  const float* x     = (const float*)d_in[0];  // [4,16,1024,16]
  const float* beta  = (const float*)d_in[1];  // [1,1,1024,1024]
  const float* theta = (const float*)d_in[2];  // [48,16]
  const float* bias  = (const float*)d_in[3];  // [16]
  const float* Lk    = (const float*)d_in[4];  // [1024,3072]
  float* out = (float*)d_out;

  prep_gemm<<<2048, 256, 0, stream>>>(x, Lk, d_ws);
  prep_attn<<<256, 256, 0, stream>>>(x, d_ws);
  gemm_mfma<<<dim3(24, 8), 512, 0, stream>>>(d_ws);
  attn_mfma<<<512, 256, 0, stream>>>(beta, d_ws);
  tail_fuse<<<256, 256, 0, stream>>>(x, theta, bias, d_ws, out);
}

// Round 10
// 180.772 us; speedup vs baseline: 1.0517x; 1.0517x over previous
//
#include <hip/hip_runtime.h>
#include <hip/hip_bf16.h>
#include <stdint.h>

// B=4, C=16, n=1024, T=16, Ks=3
// out = softmax_c( cosatt(x) * relu(Gconv(x) + x) ), [4,16,1024,16] fp32

using short8v = __attribute__((ext_vector_type(8))) short;
using float4v = __attribute__((ext_vector_type(4))) float;

#define MFMA16(a, b, c) __builtin_amdgcn_mfma_f32_16x16x32_bf16(a, b, c, 0, 0, 0)

// ---- workspace layout (bytes) -- total 46,137,344 ----
static constexpr size_t M1_OFF  = 0;          // 1024x3072 f32
static constexpr size_t OP0_OFF = 12582912;   // attn O partial, j 0..511   (4MB)
static constexpr size_t XSH_OFF = 16777216;   // x-hat S-frag layout hi  (64bc x 64rf x 64lane x 16B)
static constexpr size_t XSL_OFF = 20971520;   //                     lo
static constexpr size_t XTH_OFF = 25165824;   // RAW-x^T PV-frag layout hi (64bc x 32g32 x 64lane x 16B)
static constexpr size_t XTL_OFF = 27262976;   //                        lo
static constexpr size_t AGH_OFF = 29360128;   // GEMM A hi (dead after gemm_mfma)
static constexpr size_t OP1_OFF = AGH_OFF;    // attn O partial, j 512..1023 (4MB, reuses AGH+AGL)
static constexpr size_t AGL_OFF = 31457280;
static constexpr size_t BGH_OFF = 33554432;   // GEMM B hi (24tn x 32tk x 512ch x 16B)
static constexpr size_t BGL_OFF = 39845888;

__device__ __forceinline__ float fast_rcp(float x) {
  float r; asm("v_rcp_f32 %0, %1" : "=v"(r) : "v"(x)); return r;
}
__device__ __forceinline__ unsigned f2u(float f) { union { float f; unsigned u; } v; v.f = f; return v.u; }
__device__ __forceinline__ float u2f(unsigned u) { union { unsigned u; float f; } v; v.u = u; return v.f; }
__device__ __forceinline__ unsigned short f2bf(float f) {
  unsigned u = f2u(f);
  return (unsigned short)((u + 0x7FFFu + ((u >> 16) & 1u)) >> 16);  // RNE
}
__device__ __forceinline__ float bf2f(unsigned short h) { return u2f(((unsigned)h) << 16); }

typedef const __attribute__((address_space(1))) unsigned int* gas1_t;
typedef __attribute__((address_space(3))) unsigned int* las3_t;
__device__ __forceinline__ void gload16(const void* g, void* l) {
  __builtin_amdgcn_global_load_lds((gas1_t)g, (las3_t)l, 16, 0, 0);
}

// ---------------------------------------------------------------------------
// prep_gemm: split X_tmp and Lk into bf16 hi/lo in fragment-tile-linear order.
// ---------------------------------------------------------------------------
__global__ __launch_bounds__(256) void prep_gemm(const float* __restrict__ x,
                                                 const float* __restrict__ Lk,
                                                 void* __restrict__ ws) {
  const int n = blockIdx.x * 256 + threadIdx.x;
  short8v hv, lv;
  if (n < 131072) {  // A chunks: X_tmp[row][k] = x[(row>>4)*16384 + k*16 + (row&15)]
    const int r = n & 15, g = (n >> 4) & 3, f = (n >> 6) & 7, tk = (n >> 9) & 31, tm = n >> 14;
    const float* p = x + (size_t)(tm * 8 + f) * 16384 + (size_t)(tk * 32 + g * 8) * 16 + r;
#pragma unroll
    for (int j = 0; j < 8; ++j) {
      float v = p[j * 16];
      unsigned short h = f2bf(v);
      hv[j] = (short)h; lv[j] = (short)f2bf(v - bf2f(h));
    }
    ((short8v*)((char*)ws + AGH_OFF))[n] = hv;
    ((short8v*)((char*)ws + AGL_OFF))[n] = lv;
  } else {  // B chunks from Lk[k][col]
    const int nb = n - 131072;
    const int r = nb & 15, g = (nb >> 4) & 3, f = (nb >> 6) & 7, tk = (nb >> 9) & 31, tn = nb >> 14;
    const float* p = Lk + (size_t)(tk * 32 + g * 8) * 3072 + tn * 128 + f * 16 + r;
#pragma unroll
    for (int j = 0; j < 8; ++j) {
      float v = p[(size_t)j * 3072];
      unsigned short h = f2bf(v);
      hv[j] = (short)h; lv[j] = (short)f2bf(v - bf2f(h));
    }
    ((short8v*)((char*)ws + BGH_OFF))[nb] = hv;
    ((short8v*)((char*)ws + BGL_OFF))[nb] = lv;
  }
}

// ---------------------------------------------------------------------------
// prep_attn: XS = bf16 hi/lo of x-hat (S-operand frags, lanes>=32 zero pad);
// XT = bf16 hi/lo of RAW x transposed (PV B-frags). (R4 fix: PV uses raw x.)
// ---------------------------------------------------------------------------
__global__ __launch_bounds__(256) void prep_attn(const float* __restrict__ x,
                                                 void* __restrict__ ws) {
  __shared__ float xs[256 * 16];  // RAW x slab
  const int tid = threadIdx.x;
  const int bc = blockIdx.x >> 2, ss = blockIdx.x & 3;
  const float* xb = x + (size_t)bc * 16384 + (size_t)ss * 4096;
#pragma unroll
  for (int r = 0; r < 4; ++r) ((float4*)xs)[r * 256 + tid] = ((const float4*)xb)[r * 256 + tid];
  __syncthreads();
  float v[16];
#pragma unroll
  for (int q = 0; q < 4; ++q) {
    float4 t4 = ((float4*)xs)[tid * 4 + q];
    v[q * 4] = t4.x; v[q * 4 + 1] = t4.y; v[q * 4 + 2] = t4.z; v[q * 4 + 3] = t4.w;
  }
  float s2 = 0.f;
#pragma unroll
  for (int t = 0; t < 16; ++t) s2 += v[t] * v[t];
  const float rn = fast_rcp(sqrtf(s2));
#pragma unroll
  for (int t = 0; t < 16; ++t) v[t] *= rn;
  unsigned short hh[16], ll[16];
#pragma unroll
  for (int t = 0; t < 16; ++t) { hh[t] = f2bf(v[t]); ll[t] = f2bf(v[t] - bf2f(hh[t])); }
  short8v h0, h1, l0, l1, zz;
#pragma unroll
  for (int j = 0; j < 8; ++j) {
    h0[j] = (short)hh[j]; h1[j] = (short)hh[8 + j];
    l0[j] = (short)ll[j]; l1[j] = (short)ll[8 + j]; zz[j] = 0;
  }
  const int rf = ss * 16 + (tid >> 4);
  short8v* XSh = (short8v*)((char*)ws + XSH_OFF);
  short8v* XSl = (short8v*)((char*)ws + XSL_OFF);
  const size_t base = ((size_t)bc * 64 + rf) * 64;
  const int lo = tid & 15;
  XSh[base + lo] = h0;       XSh[base + 16 + lo] = h1;
  XSh[base + 32 + lo] = zz;  XSh[base + 48 + lo] = zz;
  XSl[base + lo] = l0;       XSl[base + 16 + lo] = l1;
  XSl[base + 32 + lo] = zz;  XSl[base + 48 + lo] = zz;
  // XT gather from RAW xs: chunk (jt_l, lane): t = lane&15, j = jt_l*32 + (lane>>4)*8 + jj
  short8v* XTh = (short8v*)((char*)ws + XTH_OFF);
  short8v* XTl = (short8v*)((char*)ws + XTL_OFF);
#pragma unroll
  for (int rep = 0; rep < 2; ++rep) {
    const int idx = rep * 256 + tid;
    const int jt_l = idx >> 6, l = idx & 63;
    const int t = l & 15, jb = jt_l * 32 + ((l >> 4) << 3);
    short8v ph, pl;
#pragma unroll
    for (int jj = 0; jj < 8; ++jj) {
      float xv = xs[(jb + jj) * 16 + t];
      unsigned short h = f2bf(xv);
      ph[jj] = (short)h; pl[jj] = (short)f2bf(xv - bf2f(h));
    }
    const size_t ci = ((size_t)bc * 32 + ss * 8 + jt_l) * 64 + l;
    XTh[ci] = ph; XTl[ci] = pl;
  }
}

// ---------------------------------------------------------------------------
// gemm_mfma: M1 = X_tmp @ Lk via split-bf16 (AhBh + AlBh + AhBl).
// 128x128 tile, 512 thr (8 waves 2x4), BK=32, double-buffered global_load_lds.
// (R5-exact — passing configuration.)
// ---------------------------------------------------------------------------
__global__ __launch_bounds__(512) void gemm_mfma(void* __restrict__ ws) {
  __shared__ unsigned short AhL[2][4096], AlL[2][4096], BhL[2][4096], BlL[2][4096];
  const int tid = threadIdx.x, lane = tid & 63, w = tid >> 6;
  const int wm = w >> 2, wn = w & 3;
  const int bn = blockIdx.x, bm = blockIdx.y;
  const short8v* Agh = (const short8v*)((char*)ws + AGH_OFF);
  const short8v* Agl = (const short8v*)((char*)ws + AGL_OFF);
  const short8v* Bgh = (const short8v*)((char*)ws + BGH_OFF);
  const short8v* Bgl = (const short8v*)((char*)ws + BGL_OFF);
  float* M1 = (float*)((char*)ws + M1_OFF);
  float4v acc[4][2] = {};

  auto stage = [&](int tk, int bb) {
    gload16(&Agh[(size_t)(bm * 32 + tk) * 512 + tid], &AhL[bb][tid * 8]);
    gload16(&Agl[(size_t)(bm * 32 + tk) * 512 + tid], &AlL[bb][tid * 8]);
    gload16(&Bgh[(size_t)(bn * 32 + tk) * 512 + tid], &BhL[bb][tid * 8]);
    gload16(&Bgl[(size_t)(bn * 32 + tk) * 512 + tid], &BlL[bb][tid * 8]);
  };
  stage(0, 0);
  __syncthreads();
  for (int tk = 0; tk < 32; ++tk) {
    const int bb = tk & 1;
    if (tk < 31) stage(tk + 1, bb ^ 1);
    short8v ah[4], al[4], bh[2], bl[2];
#pragma unroll
    for (int fm = 0; fm < 4; ++fm) {
      ah[fm] = *(const short8v*)&AhL[bb][((wm * 4 + fm) * 64 + lane) * 8];
      al[fm] = *(const short8v*)&AlL[bb][((wm * 4 + fm) * 64 + lane) * 8];
    }
#pragma unroll
    for (int fn = 0; fn < 2; ++fn) {
      bh[fn] = *(const short8v*)&BhL[bb][((wn * 2 + fn) * 64 + lane) * 8];
      bl[fn] = *(const short8v*)&BlL[bb][((wn * 2 + fn) * 64 + lane) * 8];
    }
#pragma unroll
    for (int fm = 0; fm < 4; ++fm)
#pragma unroll
      for (int fn = 0; fn < 2; ++fn) {
        acc[fm][fn] = MFMA16(ah[fm], bh[fn], acc[fm][fn]);
        acc[fm][fn] = MFMA16(al[fm], bh[fn], acc[fm][fn]);
        acc[fm][fn] = MFMA16(ah[fm], bl[fn], acc[fm][fn]);
      }
    __syncthreads();
  }
  // C/D: col = lane&15, row = (lane>>4)*4 + reg  (R2-verified)
#pragma unroll
  for (int fm = 0; fm < 4; ++fm)
#pragma unroll
    for (int fn = 0; fn < 2; ++fn) {
      const int col = bn * 128 + (wn * 2 + fn) * 16 + (lane & 15);
      const int rowb = bm * 128 + (wm * 4 + fm) * 16 + ((lane >> 4) << 2);
#pragma unroll
      for (int r = 0; r < 4; ++r) M1[(size_t)(rowb + r) * 3072 + col] = acc[fm][fn][r];
    }
}

// ---------------------------------------------------------------------------
// attn_mfma: R9-exact passing structure, ONE bounded change: j-range split in
// half across 2x blocks (grid 512 -> 1024) for 4 resident blocks/CU (50% occ
// ceiling vs R9's grid-limited 25%). Each block writes a partial O for its
// j-half; tail_fuse sums the two partials. Partial 1 reuses the GEMM operand
// scratch (dead after gemm_mfma; same-stream ordering guarantees).
// ---------------------------------------------------------------------------
__global__ __launch_bounds__(256, 4) void attn_mfma(const float* __restrict__ beta,
                                                    void* __restrict__ ws) {
  __shared__ unsigned short XShL[2][4096], XSlL[2][4096];  // 16KB + 16KB
  __shared__ unsigned short Pbuf[4][1024];  // per-wave: Ph [0..511], Pl [512..1023]
  const int tid = threadIdx.x, lane = tid & 63, w = tid >> 6;
  const int bc = blockIdx.x >> 4, slab = (blockIdx.x >> 1) & 7, jhalf = blockIdx.x & 1;
  const int jt0 = jhalf * 4;
  const short8v* XSgh = (const short8v*)((char*)ws + XSH_OFF);
  const short8v* XSgl = (const short8v*)((char*)ws + XSL_OFF);
  const short8v* XTgh = (const short8v*)((char*)ws + XTH_OFF);
  const short8v* XTgl = (const short8v*)((char*)ws + XTL_OFF);
  float* O = (float*)((char*)ws + (jhalf ? OP1_OFF : OP0_OFF));

  short8v ah[2], al[2];
#pragma unroll
  for (int m = 0; m < 2; ++m) {
    const int ifr = slab * 8 + w * 2 + m;
    ah[m] = XSgh[((size_t)bc * 64 + ifr) * 64 + lane];
    al[m] = XSgl[((size_t)bc * 64 + ifr) * 64 + lane];
  }
  float4v o[2] = {};

  auto stage = [&](int jt, int bb) {
    const short8v* sh = XSgh + (size_t)bc * 4096 + jt * 512;
    const short8v* sl = XSgl + (size_t)bc * 4096 + jt * 512;
    gload16(&sh[tid], &XShL[bb][tid * 8]);
    gload16(&sh[256 + tid], &XShL[bb][(256 + tid) * 8]);
    gload16(&sl[tid], &XSlL[bb][tid * 8]);
    gload16(&sl[256 + tid], &XSlL[bb][(256 + tid) * 8]);
  };
  stage(jt0, 0);
  __syncthreads();

  unsigned short* pb = &Pbuf[w][0];
  for (int jt = jt0; jt < jt0 + 4; ++jt) {
    const int bb = (jt - jt0) & 1;
    if (jt < jt0 + 3) stage(jt + 1, bb ^ 1);
    // PV B-operands: per-lane register loads (same chunk math as R5's staging)
    short8v xth[4], xtl[4];
#pragma unroll
    for (int kk = 0; kk < 4; ++kk) {
      xth[kk] = XTgh[(size_t)bc * 2048 + jt * 256 + kk * 64 + lane];
      xtl[kk] = XTgl[(size_t)bc * 2048 + jt * 256 + kk * 64 + lane];
    }
#pragma unroll
    for (int m = 0; m < 2; ++m) {
      const int ib = slab * 128 + (w * 2 + m) * 16 + ((lane >> 4) << 2);
#pragma unroll
      for (int kk = 0; kk < 4; ++kk) {
#pragma unroll
        for (int fh = 0; fh < 2; ++fh) {
          const int f = kk * 2 + fh;
          short8v bhv = *(const short8v*)&XShL[bb][(f * 64 + lane) * 8];
          short8v blv = *(const short8v*)&XSlL[bb][(f * 64 + lane) * 8];
          float4v s = {0.f, 0.f, 0.f, 0.f};
          s = MFMA16(ah[m], bhv, s);
          s = MFMA16(al[m], bhv, s);
          s = MFMA16(ah[m], blv, s);
          const float* bp = beta + (size_t)ib * 1024 + jt * 128 + f * 16 + (lane & 15);
#pragma unroll
          for (int r = 0; r < 4; ++r) {
            const float z = bp[(size_t)r * 1024] * s[r];   // beta * cos
            const float p = fast_rcp(1.f + __expf(-z));    // sigmoid
            const unsigned short ph = f2bf(p);
            const unsigned short pl = f2bf(p - bf2f(ph));
            const int i = ((lane >> 4) << 2) + r;
            const int jl = fh * 16 + (lane & 15);
            const int sidx = (((jl >> 3) << 4) | i) * 8 + (jl & 7);  // frag-linear
            pb[sidx] = ph;
            pb[512 + sidx] = pl;
          }
        }
        short8v pha = *(const short8v*)&pb[lane * 8];
        short8v pla = *(const short8v*)&pb[512 + lane * 8];
        o[m] = MFMA16(pha, xth[kk], o[m]);
        o[m] = MFMA16(pla, xth[kk], o[m]);
        o[m] = MFMA16(pha, xtl[kk], o[m]);
      }
    }
    __syncthreads();
  }
#pragma unroll
  for (int m = 0; m < 2; ++m)
#pragma unroll
    for (int r = 0; r < 4; ++r) {
      const int ig = slab * 128 + (w * 2 + m) * 16 + ((lane >> 4) << 2) + r;
      O[((size_t)bc * 1024 + ig) * 16 + (lane & 15)] = o[m][r];
    }
}

// ---------------------------------------------------------------------------
// tail_fuse: O = OP0 + OP1; g = theta-contraction of M1 (LDS-staged slab),
// logit = O * relu(g + x), softmax over c in-register via 16-lane shfl_xor.
// ---------------------------------------------------------------------------
__global__ __launch_bounds__(256) void tail_fuse(const float* __restrict__ x,
                                                 const float* __restrict__ theta,
                                                 const float* __restrict__ bias,
                                                 const void* __restrict__ ws,
                                                 float* __restrict__ out) {
  __shared__ float m1s[48 * 256];  // [tauk][t][i]
  __shared__ float ths[768];
  const int tid = threadIdx.x;
  const int b = blockIdx.x >> 6, chunk = blockIdx.x & 63, i0 = chunk * 16;
  const float* M1 = (const float*)((const char*)ws + M1_OFF);
  const float* O0 = (const float*)((const char*)ws + OP0_OFF);
  const float* O1 = (const float*)((const char*)ws + OP1_OFF);
  {
    const int i = tid & 15, t = tid >> 4;
#pragma unroll
    for (int s = 0; s < 48; ++s)
      m1s[(s * 16 + t) * 16 + i] =
          M1[(size_t)((b * 16 + t) * 16 + s / 3) * 3072 + (s % 3) * 1024 + i0 + i];
  }
#pragma unroll
  for (int r = 0; r < 3; ++r) ths[r * 256 + tid] = theta[r * 256 + tid];
  __syncthreads();
  const int c = tid & 15, t = tid >> 4;
  const int bc = b * 16 + c;
  float xv[16], ov[16];
#pragma unroll
  for (int i = 0; i < 16; ++i) {
    const size_t a = ((size_t)bc * 1024 + i0 + i) * 16 + t;
    xv[i] = x[a]; ov[i] = O0[a] + O1[a];
  }
  float thc[48];
#pragma unroll
  for (int s = 0; s < 48; ++s) thc[s] = ths[s * 16 + c];
  float g[16];
  const float bs = bias[c];
#pragma unroll
  for (int i = 0; i < 16; ++i) g[i] = bs;
#pragma unroll
  for (int s = 0; s < 48; ++s) {
    const float4* mp = (const float4*)&m1s[(s * 16 + t) * 16];
    const float th = thc[s];
#pragma unroll
    for (int q = 0; q < 4; ++q) {
      float4 mv = mp[q];
      g[q * 4] += mv.x * th; g[q * 4 + 1] += mv.y * th;
      g[q * 4 + 2] += mv.z * th; g[q * 4 + 3] += mv.w * th;
    }
  }
  float lg[16];
#pragma unroll
  for (int i = 0; i < 16; ++i) lg[i] = ov[i] * fmaxf(g[i] + xv[i], 0.f);
#pragma unroll
  for (int i = 0; i < 16; ++i) {
    float mx = lg[i];
    mx = fmaxf(mx, __shfl_xor(mx, 1)); mx = fmaxf(mx, __shfl_xor(mx, 2));
    mx = fmaxf(mx, __shfl_xor(mx, 4)); mx = fmaxf(mx, __shfl_xor(mx, 8));
    const float e = __expf(lg[i] - mx);
    float sm = e;
    sm += __shfl_xor(sm, 1); sm += __shfl_xor(sm, 2);
    sm += __shfl_xor(sm, 4); sm += __shfl_xor(sm, 8);
    out[((size_t)bc * 1024 + i0 + i) * 16 + t] = e * fast_rcp(sm);
  }
}

// ---------------------------------------------------------------------------
extern "C" void kernel_launch(void* const* d_in, const int* in_sizes, int n_in,
                              void* d_out, int out_size, void* d_ws, size_t ws_size,
                              hipStream_t stream) {
  const float* x     = (const float*)d_in[0];  // [4,16,1024,16]
  const float* beta  = (const float*)d_in[1];  // [1,1,1024,1024]
  const float* theta = (const float*)d_in[2];  // [48,16]
  const float* bias  = (const float*)d_in[3];  // [16]
  const float* Lk    = (const float*)d_in[4];  // [1024,3072]
  float* out = (float*)d_out;

  prep_gemm<<<2048, 256, 0, stream>>>(x, Lk, d_ws);
  prep_attn<<<256, 256, 0, stream>>>(x, d_ws);
  gemm_mfma<<<dim3(24, 8), 512, 0, stream>>>(d_ws);
  attn_mfma<<<1024, 256, 0, stream>>>(beta, d_ws);
  tail_fuse<<<256, 256, 0, stream>>>(x, theta, bias, d_ws, out);
}